// Round 1
// baseline (838.891 us; speedup 1.0000x reference)
//
#include <hip/hip_runtime.h>
#include <math.h>

static constexpr int Bn = 8;
static constexpr int Cn = 256;
static constexpr int Sn = 16384;   // 128*128

// ---------------- Kernel 1: partial Gram (energy) with atomic accumulate ----
// energy[b][c][d] = sum_s v[b,c,s] * v[b,d,s]
// tile 128x128 over (c,d), K split into 16 slices of 1024, LDS chunks of 32.
static constexpr int TILE   = 128;
static constexpr int KSPLIT = 16;
static constexpr int KSLICE = Sn / KSPLIT;  // 1024
static constexpr int KB     = 32;

__global__ __launch_bounds__(256) void gram_kernel(const float* __restrict__ x,
                                                   float* __restrict__ energy) {
  const int b   = blockIdx.z;
  const int tij = blockIdx.y;             // 0..3 -> (ti,tj) in 2x2
  const int ti  = tij >> 1, tj = tij & 1;
  const int kk  = blockIdx.x;             // k-slice

  const float* vb    = x + (size_t)b * Cn * Sn;
  const float* Abase = vb + (size_t)(ti * TILE) * Sn + kk * KSLICE;
  const float* Bbase = vb + (size_t)(tj * TILE) * Sn + kk * KSLICE;

  __shared__ float Ta[KB][TILE + 4];   // [k][row], padded
  __shared__ float Tb[KB][TILE + 4];

  const int t  = threadIdx.x;          // 0..255
  const int tx = t & 15;               // d micro-tile
  const int ty = t >> 4;               // c micro-tile

  float acc[8][8];
#pragma unroll
  for (int i = 0; i < 8; i++)
#pragma unroll
    for (int j = 0; j < 8; j++) acc[i][j] = 0.f;

  for (int kc = 0; kc < KSLICE; kc += KB) {
    // stage 128 rows x 32 floats, transposed into LDS
#pragma unroll
    for (int it = 0; it < 4; it++) {
      int idx = t + it * 256;          // 0..1023
      int row = idx >> 3;              // 0..127
      int kq  = idx & 7;               // float4 index within 32-float chunk
      float4 av = *(const float4*)(Abase + (size_t)row * Sn + kc + kq * 4);
      float4 bv = *(const float4*)(Bbase + (size_t)row * Sn + kc + kq * 4);
      Ta[kq * 4 + 0][row] = av.x; Ta[kq * 4 + 1][row] = av.y;
      Ta[kq * 4 + 2][row] = av.z; Ta[kq * 4 + 3][row] = av.w;
      Tb[kq * 4 + 0][row] = bv.x; Tb[kq * 4 + 1][row] = bv.y;
      Tb[kq * 4 + 2][row] = bv.z; Tb[kq * 4 + 3][row] = bv.w;
    }
    __syncthreads();

#pragma unroll
    for (int k = 0; k < KB; k++) {
      float a0[8], b0[8];
      *(float4*)&a0[0] = *(const float4*)&Ta[k][ty * 8];
      *(float4*)&a0[4] = *(const float4*)&Ta[k][ty * 8 + 4];
      *(float4*)&b0[0] = *(const float4*)&Tb[k][tx * 8];
      *(float4*)&b0[4] = *(const float4*)&Tb[k][tx * 8 + 4];
#pragma unroll
      for (int i = 0; i < 8; i++)
#pragma unroll
        for (int j = 0; j < 8; j++) acc[i][j] += a0[i] * b0[j];
    }
    __syncthreads();
  }

  float* eb = energy + ((size_t)b * Cn + ti * TILE) * Cn + tj * TILE;
#pragma unroll
  for (int i = 0; i < 8; i++)
#pragma unroll
    for (int j = 0; j < 8; j++)
      atomicAdd(&eb[(size_t)(ty * 8 + i) * Cn + tx * 8 + j], acc[i][j]);
}

// ---------------- Kernel 2: reduce + softmax ----------------
// softmax(max_d(e) - e) over d  ==  exp(e_min - e_d) / sum  (row max cancels)
__global__ __launch_bounds__(256) void softmax_kernel(float* __restrict__ energy) {
  const int row = blockIdx.x;          // b*Cn + c
  const int t   = threadIdx.x;
  float e = energy[(size_t)row * Cn + t];

  __shared__ float red[256];
  red[t] = e;
  __syncthreads();
  for (int s = 128; s > 0; s >>= 1) {
    if (t < s) red[t] = fminf(red[t], red[t + s]);
    __syncthreads();
  }
  float emin = red[0];
  __syncthreads();

  float p = expf(emin - e);
  red[t] = p;
  __syncthreads();
  for (int s = 128; s > 0; s >>= 1) {
    if (t < s) red[t] += red[t + s];
    __syncthreads();
  }
  float inv = 1.f / red[0];
  energy[(size_t)row * Cn + t] = p * inv;   // in-place: energy becomes w
}

// ---------------- Kernel 3: y = w @ v, out = alpha*y + x ----------------
// A = w[b] (256x256, K=d), B = v[b] (256x16384). Tile 64(M) x 128(N), K chunks of 32.
static constexpr int MT = 64;
static constexpr int NT = 128;
static constexpr int KB3 = 32;

__global__ __launch_bounds__(256) void ygemm_kernel(const float* __restrict__ w,
                                                    const float* __restrict__ x,
                                                    const float* __restrict__ alpha,
                                                    float* __restrict__ out) {
  const int b  = blockIdx.z;
  const int m0 = blockIdx.y * MT;
  const int s0 = blockIdx.x * NT;

  const float* Ab = w + ((size_t)b * Cn + m0) * Cn;       // A[m][k], k contiguous
  const float* Bb = x + (size_t)b * Cn * Sn + s0;         // B[k][n], n contiguous

  __shared__ float At[KB3][MT + 4];    // [k][m]
  __shared__ float Bt[KB3][NT + 4];    // [k][n]

  const int t  = threadIdx.x;
  const int tx = t & 15;               // n micro: tx*8
  const int ty = t >> 4;               // m micro: ty*4

  float acc[4][8];
#pragma unroll
  for (int i = 0; i < 4; i++)
#pragma unroll
    for (int j = 0; j < 8; j++) acc[i][j] = 0.f;

  for (int kc = 0; kc < Cn; kc += KB3) {
    // A chunk: 64 rows x 32 k = 512 float4 -> 2 per thread, store transposed
#pragma unroll
    for (int it = 0; it < 2; it++) {
      int idx = t + it * 256;          // 0..511
      int row = idx >> 3;              // 0..63
      int kq  = idx & 7;
      float4 av = *(const float4*)(Ab + (size_t)row * Cn + kc + kq * 4);
      At[kq * 4 + 0][row] = av.x; At[kq * 4 + 1][row] = av.y;
      At[kq * 4 + 2][row] = av.z; At[kq * 4 + 3][row] = av.w;
    }
    // B chunk: 32 k-rows x 128 n = 1024 float4 -> 4 per thread, natural layout
#pragma unroll
    for (int it = 0; it < 4; it++) {
      int idx = t + it * 256;          // 0..1023
      int k   = idx >> 5;              // 0..31
      int nq  = idx & 31;              // float4 within 128 floats
      float4 bv = *(const float4*)(Bb + (size_t)(kc + k) * Sn + nq * 4);
      *(float4*)&Bt[k][nq * 4] = bv;
    }
    __syncthreads();

#pragma unroll
    for (int k = 0; k < KB3; k++) {
      float a0[4], b0[8];
      *(float4*)&a0[0] = *(const float4*)&At[k][ty * 4];
      *(float4*)&b0[0] = *(const float4*)&Bt[k][tx * 8];
      *(float4*)&b0[4] = *(const float4*)&Bt[k][tx * 8 + 4];
#pragma unroll
      for (int i = 0; i < 4; i++)
#pragma unroll
        for (int j = 0; j < 8; j++) acc[i][j] += a0[i] * b0[j];
    }
    __syncthreads();
  }

  const float al = alpha[0];
  const float* xb = x   + ((size_t)b * Cn + m0) * Sn + s0;
  float*       ob = out + ((size_t)b * Cn + m0) * Sn + s0;
#pragma unroll
  for (int i = 0; i < 4; i++) {
    int m = ty * 4 + i;
    float4 x0 = *(const float4*)(xb + (size_t)m * Sn + tx * 8);
    float4 x1 = *(const float4*)(xb + (size_t)m * Sn + tx * 8 + 4);
    float4 o0, o1;
    o0.x = al * acc[i][0] + x0.x; o0.y = al * acc[i][1] + x0.y;
    o0.z = al * acc[i][2] + x0.z; o0.w = al * acc[i][3] + x0.w;
    o1.x = al * acc[i][4] + x1.x; o1.y = al * acc[i][5] + x1.y;
    o1.z = al * acc[i][6] + x1.z; o1.w = al * acc[i][7] + x1.w;
    *(float4*)(ob + (size_t)m * Sn + tx * 8)     = o0;
    *(float4*)(ob + (size_t)m * Sn + tx * 8 + 4) = o1;
  }
}

extern "C" void kernel_launch(void* const* d_in, const int* in_sizes, int n_in,
                              void* d_out, int out_size, void* d_ws, size_t ws_size,
                              hipStream_t stream) {
  const float* x     = (const float*)d_in[0];
  const float* alpha = (const float*)d_in[1];
  float*       out   = (float*)d_out;
  float*       energy = (float*)d_ws;          // B*C*C fp32 = 2 MB; becomes w in-place

  const size_t energy_bytes = (size_t)Bn * Cn * Cn * sizeof(float);
  hipMemsetAsync(energy, 0, energy_bytes, stream);

  dim3 g1(KSPLIT, 4, Bn);                      // 16 x 4 x 8 = 512 blocks
  gram_kernel<<<g1, 256, 0, stream>>>(x, energy);

  softmax_kernel<<<Bn * Cn, 256, 0, stream>>>(energy);

  dim3 g3(Sn / NT, Cn / MT, Bn);               // 128 x 4 x 8 = 4096 blocks
  ygemm_kernel<<<g3, 256, 0, stream>>>(energy, x, alpha, out);
}

// Round 2
// 445.996 us; speedup vs baseline: 1.8809x; 1.8809x over previous
//
#include <hip/hip_runtime.h>
#include <math.h>

static constexpr int Bn = 8;
static constexpr int Cn = 256;
static constexpr int Sn = 16384;   // 128*128

typedef __bf16 bf16x4 __attribute__((ext_vector_type(4)));
typedef __bf16 bf16x8 __attribute__((ext_vector_type(8)));
typedef float  f32x4  __attribute__((ext_vector_type(4)));

// ---------------- Kernel 1: partial Gram (energy) via split-bf16 MFMA -------
// energy[b][c][d] = sum_s v[b,c,s] * v[b,d,s]
// x = hi + lo (bf16 split); energy ~= hi.hi^T + hi.lo^T + lo.hi^T (fp32 acc).
// Block tile 128x128 over (c,d); K split into 16 slices of 1024; LDS chunks of 32.
static constexpr int TILE   = 128;
static constexpr int KSPLIT = 16;
static constexpr int KSLICE = Sn / KSPLIT;  // 1024
static constexpr int KB     = 32;
static constexpr int LP     = 56;           // LDS row stride in bf16 (112 B: 16B-aligned, conflict-free partition)

__global__ __launch_bounds__(256, 2) void gram_kernel(const float* __restrict__ x,
                                                      float* __restrict__ energy) {
  const int b   = blockIdx.z;
  const int tij = blockIdx.y;             // 0..3 -> (ti,tj) in 2x2
  const int ti  = tij >> 1, tj = tij & 1;
  const int kk  = blockIdx.x;             // k-slice

  const float* vb    = x + (size_t)b * Cn * Sn;
  const float* Abase = vb + (size_t)(ti * TILE) * Sn + kk * KSLICE;
  const float* Bbase = vb + (size_t)(tj * TILE) * Sn + kk * KSLICE;

  __shared__ __align__(16) __bf16 Ah[TILE * LP];
  __shared__ __align__(16) __bf16 Al[TILE * LP];
  __shared__ __align__(16) __bf16 Bh[TILE * LP];
  __shared__ __align__(16) __bf16 Bl[TILE * LP];

  const int t    = threadIdx.x;           // 0..255
  const int lane = t & 63;
  const int wv   = t >> 6;                // wave 0..3
  const int wr   = wv >> 1;               // wave row (c) in 2x2 of 64x64
  const int wc   = wv & 1;                // wave col (d)
  const int ln   = lane & 15;
  const int quad = lane >> 4;             // 0..3

  f32x4 acc[4][4];
#pragma unroll
  for (int i = 0; i < 4; i++)
#pragma unroll
    for (int j = 0; j < 4; j++) acc[i][j] = (f32x4){0.f, 0.f, 0.f, 0.f};

  for (int kc = 0; kc < KSLICE; kc += KB) {
    // stage 128 rows x 32 k, fp32 -> (hi,lo) bf16 into LDS
#pragma unroll
    for (int it = 0; it < 4; it++) {
      int idx = t + it * 256;             // 0..1023
      int row = idx >> 3;                 // 0..127
      int kq  = idx & 7;                  // float4 index within 32
      float4 av = *(const float4*)(Abase + (size_t)row * Sn + kc + kq * 4);
      float4 bv = *(const float4*)(Bbase + (size_t)row * Sn + kc + kq * 4);
      bf16x4 ah, al4, bh, bl4;
      {
        __bf16 h0 = (__bf16)av.x, h1 = (__bf16)av.y, h2 = (__bf16)av.z, h3 = (__bf16)av.w;
        ah  = (bf16x4){h0, h1, h2, h3};
        al4 = (bf16x4){(__bf16)(av.x - (float)h0), (__bf16)(av.y - (float)h1),
                       (__bf16)(av.z - (float)h2), (__bf16)(av.w - (float)h3)};
      }
      {
        __bf16 h0 = (__bf16)bv.x, h1 = (__bf16)bv.y, h2 = (__bf16)bv.z, h3 = (__bf16)bv.w;
        bh  = (bf16x4){h0, h1, h2, h3};
        bl4 = (bf16x4){(__bf16)(bv.x - (float)h0), (__bf16)(bv.y - (float)h1),
                       (__bf16)(bv.z - (float)h2), (__bf16)(bv.w - (float)h3)};
      }
      *(bf16x4*)&Ah[row * LP + kq * 4] = ah;
      *(bf16x4*)&Al[row * LP + kq * 4] = al4;
      *(bf16x4*)&Bh[row * LP + kq * 4] = bh;
      *(bf16x4*)&Bl[row * LP + kq * 4] = bl4;
    }
    __syncthreads();

    // frags: A rows wr*64 + i*16 + ln; B rows wc*64 + j*16 + ln; k = quad*8..+7
    bf16x8 fah[4], fal[4], fbh[4], fbl[4];
#pragma unroll
    for (int i = 0; i < 4; i++) {
      int ar = wr * 64 + i * 16 + ln;
      int br = wc * 64 + i * 16 + ln;
      fah[i] = *(const bf16x8*)&Ah[ar * LP + quad * 8];
      fal[i] = *(const bf16x8*)&Al[ar * LP + quad * 8];
      fbh[i] = *(const bf16x8*)&Bh[br * LP + quad * 8];
      fbl[i] = *(const bf16x8*)&Bl[br * LP + quad * 8];
    }
#pragma unroll
    for (int i = 0; i < 4; i++)
#pragma unroll
      for (int j = 0; j < 4; j++) {
        acc[i][j] = __builtin_amdgcn_mfma_f32_16x16x32_bf16(fah[i], fbh[j], acc[i][j], 0, 0, 0);
        acc[i][j] = __builtin_amdgcn_mfma_f32_16x16x32_bf16(fah[i], fbl[j], acc[i][j], 0, 0, 0);
        acc[i][j] = __builtin_amdgcn_mfma_f32_16x16x32_bf16(fal[i], fbh[j], acc[i][j], 0, 0, 0);
      }
    __syncthreads();
  }

  // epilogue: C/D layout col=lane&15, row=quad*4+reg (m89-verified)
  float* eb = energy + ((size_t)b * Cn + ti * TILE) * Cn + tj * TILE;
#pragma unroll
  for (int i = 0; i < 4; i++)
#pragma unroll
    for (int j = 0; j < 4; j++) {
      int c0 = wr * 64 + i * 16 + quad * 4;
      int d  = wc * 64 + j * 16 + ln;
#pragma unroll
      for (int r = 0; r < 4; r++)
        atomicAdd(&eb[(size_t)(c0 + r) * Cn + d], acc[i][j][r]);
    }
}

// ---------------- Kernel 2: reduce + softmax ----------------
// softmax(max_d(e) - e) over d  ==  exp(e_min - e_d) / sum  (row max cancels)
__global__ __launch_bounds__(256) void softmax_kernel(float* __restrict__ energy) {
  const int row = blockIdx.x;          // b*Cn + c
  const int t   = threadIdx.x;
  float e = energy[(size_t)row * Cn + t];

  __shared__ float red[256];
  red[t] = e;
  __syncthreads();
  for (int s = 128; s > 0; s >>= 1) {
    if (t < s) red[t] = fminf(red[t], red[t + s]);
    __syncthreads();
  }
  float emin = red[0];
  __syncthreads();

  float p = expf(emin - e);
  red[t] = p;
  __syncthreads();
  for (int s = 128; s > 0; s >>= 1) {
    if (t < s) red[t] += red[t + s];
    __syncthreads();
  }
  float inv = 1.f / red[0];
  energy[(size_t)row * Cn + t] = p * inv;   // in-place: energy becomes w
}

// ---------------- Kernel 3: y = w @ v, out = alpha*y + x ----------------
// A = w[b] (256x256, K=d), B = v[b] (256x16384). Tile 64(M) x 128(N), K chunks of 32.
static constexpr int MT = 64;
static constexpr int NT = 128;
static constexpr int KB3 = 32;

__global__ __launch_bounds__(256) void ygemm_kernel(const float* __restrict__ w,
                                                    const float* __restrict__ x,
                                                    const float* __restrict__ alpha,
                                                    float* __restrict__ out) {
  const int b  = blockIdx.z;
  const int m0 = blockIdx.y * MT;
  const int s0 = blockIdx.x * NT;

  const float* Ab = w + ((size_t)b * Cn + m0) * Cn;       // A[m][k], k contiguous
  const float* Bb = x + (size_t)b * Cn * Sn + s0;         // B[k][n], n contiguous

  __shared__ float At[KB3][MT + 4];    // [k][m]
  __shared__ float Bt[KB3][NT + 4];    // [k][n]

  const int t  = threadIdx.x;
  const int tx = t & 15;               // n micro: tx*8
  const int ty = t >> 4;               // m micro: ty*4

  float acc[4][8];
#pragma unroll
  for (int i = 0; i < 4; i++)
#pragma unroll
    for (int j = 0; j < 8; j++) acc[i][j] = 0.f;

  for (int kc = 0; kc < Cn; kc += KB3) {
    // A chunk: 64 rows x 32 k = 512 float4 -> 2 per thread, store transposed
#pragma unroll
    for (int it = 0; it < 2; it++) {
      int idx = t + it * 256;          // 0..511
      int row = idx >> 3;              // 0..63
      int kq  = idx & 7;
      float4 av = *(const float4*)(Ab + (size_t)row * Cn + kc + kq * 4);
      At[kq * 4 + 0][row] = av.x; At[kq * 4 + 1][row] = av.y;
      At[kq * 4 + 2][row] = av.z; At[kq * 4 + 3][row] = av.w;
    }
    // B chunk: 32 k-rows x 128 n = 1024 float4 -> 4 per thread, natural layout
#pragma unroll
    for (int it = 0; it < 4; it++) {
      int idx = t + it * 256;          // 0..1023
      int k   = idx >> 5;              // 0..31
      int nq  = idx & 31;              // float4 within 128 floats
      float4 bv = *(const float4*)(Bb + (size_t)(kc + k) * Sn + nq * 4);
      *(float4*)&Bt[k][nq * 4] = bv;
    }
    __syncthreads();

#pragma unroll
    for (int k = 0; k < KB3; k++) {
      float a0[4], b0[8];
      *(float4*)&a0[0] = *(const float4*)&At[k][ty * 4];
      *(float4*)&b0[0] = *(const float4*)&Bt[k][tx * 8];
      *(float4*)&b0[4] = *(const float4*)&Bt[k][tx * 8 + 4];
#pragma unroll
      for (int i = 0; i < 4; i++)
#pragma unroll
        for (int j = 0; j < 8; j++) acc[i][j] += a0[i] * b0[j];
    }
    __syncthreads();
  }

  const float al = alpha[0];
  const float* xb = x   + ((size_t)b * Cn + m0) * Sn + s0;
  float*       ob = out + ((size_t)b * Cn + m0) * Sn + s0;
#pragma unroll
  for (int i = 0; i < 4; i++) {
    int m = ty * 4 + i;
    float4 x0 = *(const float4*)(xb + (size_t)m * Sn + tx * 8);
    float4 x1 = *(const float4*)(xb + (size_t)m * Sn + tx * 8 + 4);
    float4 o0, o1;
    o0.x = al * acc[i][0] + x0.x; o0.y = al * acc[i][1] + x0.y;
    o0.z = al * acc[i][2] + x0.z; o0.w = al * acc[i][3] + x0.w;
    o1.x = al * acc[i][4] + x1.x; o1.y = al * acc[i][5] + x1.y;
    o1.z = al * acc[i][6] + x1.z; o1.w = al * acc[i][7] + x1.w;
    *(float4*)(ob + (size_t)m * Sn + tx * 8)     = o0;
    *(float4*)(ob + (size_t)m * Sn + tx * 8 + 4) = o1;
  }
}

extern "C" void kernel_launch(void* const* d_in, const int* in_sizes, int n_in,
                              void* d_out, int out_size, void* d_ws, size_t ws_size,
                              hipStream_t stream) {
  const float* x     = (const float*)d_in[0];
  const float* alpha = (const float*)d_in[1];
  float*       out   = (float*)d_out;
  float*       energy = (float*)d_ws;          // B*C*C fp32 = 2 MB; becomes w in-place

  const size_t energy_bytes = (size_t)Bn * Cn * Cn * sizeof(float);
  hipMemsetAsync(energy, 0, energy_bytes, stream);

  dim3 g1(KSPLIT, 4, Bn);                      // 16 x 4 x 8 = 512 blocks
  gram_kernel<<<g1, 256, 0, stream>>>(x, energy);

  softmax_kernel<<<Bn * Cn, 256, 0, stream>>>(energy);

  dim3 g3(Sn / NT, Cn / MT, Bn);               // 128 x 4 x 8 = 4096 blocks
  ygemm_kernel<<<g3, 256, 0, stream>>>(energy, x, alpha, out);
}